// Round 2
// baseline (83.791 us; speedup 1.0000x reference)
//
#include <hip/hip_runtime.h>
#include <cmath>

#define B_ 4
#define L_ 8192
#define N_ 16
#define H_ 64

// ---------------------------------------------------------------------------
// Kernel A: per-row segment-reset positions.
// One block per batch row. Inclusive cumsum of the 8192 int64 lengths into
// LDS (int32, sum <= 8192), then per-element binary search (searchsorted
// right) to find its segment; pos[j] = j - excl_csum[seg], 0 past the total.
// ---------------------------------------------------------------------------
__global__ void pos_kernel(const long long* __restrict__ idx,
                           float* __restrict__ pos) {
    __shared__ int csum[L_];
    __shared__ int partial[257];
    const int b   = blockIdx.x;
    const int tid = threadIdx.x;          // 256 threads
    constexpr int CHUNK = L_ / 256;       // 32 lengths per thread

    const long long* row = idx + (size_t)b * L_;

    // local inclusive scan of this thread's chunk
    int local[CHUNK];
    int s = 0;
#pragma unroll
    for (int i = 0; i < CHUNK; ++i) {
        s += (int)row[tid * CHUNK + i];
        local[i] = s;
    }
    partial[tid + 1] = s;
    if (tid == 0) partial[0] = 0;
    __syncthreads();

    // serial scan of 256 per-thread totals (loads independent of acc chain)
    if (tid == 0) {
        int acc = 0;
        for (int i = 1; i <= 256; ++i) { acc += partial[i]; partial[i] = acc; }
    }
    __syncthreads();

    const int off = partial[tid];
#pragma unroll
    for (int i = 0; i < CHUNK; ++i) csum[tid * CHUNK + i] = off + local[i];
    __syncthreads();

    const int total = csum[L_ - 1];

    for (int j = tid; j < L_; j += 256) {
        float p = 0.f;
        if (j < total) {
            // first index with csum[idx] > j  (searchsorted side='right')
            int lo = 0, hi = L_ - 1;
            while (lo < hi) {
                int mid = (lo + hi) >> 1;
                if (csum[mid] > j) hi = mid; else lo = mid + 1;
            }
            const int excl = lo ? csum[lo - 1] : 0;   // segment start offset
            p = (float)(j - excl);
        }
        pos[(size_t)b * L_ + j] = p;
    }
}

// ---------------------------------------------------------------------------
// Kernel B: streaming RoPE, trig amortized over 8 heads per thread.
// Thread (bl, hh, q) computes 4 sin/cos pairs ONCE (hardware v_sin/v_cos in
// revolutions with fract reduction), then applies them to heads
// n = hh*8 .. hh*8+7:
//   out[h]    = x[h]*cos - x[h+32]*sin
//   out[h+32] = x[h+32]*cos + x[h]*sin
// ---------------------------------------------------------------------------
__global__ void rope_kernel(const float* __restrict__ x,
                            const float* __restrict__ pos,
                            float* __restrict__ out) {
    const size_t t  = (size_t)blockIdx.x * blockDim.x + threadIdx.x;
    const int    q  = (int)(t & 7);        // which quad of the 32 pairs
    const int    hh = (int)((t >> 3) & 1); // head half (0: n=0..7, 1: n=8..15)
    const size_t bl = t >> 4;              // b*L + l

    const float p = pos[bl];

    // inv_freq[k] = 10000^(-k/32); phase in revolutions = p*inv_freq/(2*pi)
    constexpr float NEG_LN_BASE_OVER_32 = -0.28782313662425f; // -ln(10000)/32
    constexpr float INV_2PI             = 0.15915493667126f;  // 1/(2*pi)

    float sv[4], cv[4];
#pragma unroll
    for (int j = 0; j < 4; ++j) {
        const float f  = __expf((float)(q * 4 + j) * NEG_LN_BASE_OVER_32);
        float ph = p * f * INV_2PI;
        ph -= floorf(ph);                  // v_fract-style reduction
        sv[j] = __builtin_amdgcn_sinf(ph); // v_sin_f32: sin(2*pi*ph)
        cv[j] = __builtin_amdgcn_cosf(ph); // v_cos_f32
    }

    const size_t base0 = (bl * N_ + (size_t)(hh * 8)) * H_ + (size_t)(q * 4);
#pragma unroll
    for (int n = 0; n < 8; ++n) {
        const size_t base = base0 + (size_t)n * H_;
        const float4 a = *(const float4*)(x + base);        // x1 part
        const float4 b = *(const float4*)(x + base + 32);   // x2 part
        float4 o1, o2;
#pragma unroll
        for (int j = 0; j < 4; ++j) {
            const float xa = (&a.x)[j];
            const float xb = (&b.x)[j];
            (&o1.x)[j] = xa * cv[j] - xb * sv[j];
            (&o2.x)[j] = xb * cv[j] + xa * sv[j];
        }
        *(float4*)(out + base)      = o1;
        *(float4*)(out + base + 32) = o2;
    }
}

extern "C" void kernel_launch(void* const* d_in, const int* in_sizes, int n_in,
                              void* d_out, int out_size, void* d_ws, size_t ws_size,
                              hipStream_t stream) {
    const float*     x   = (const float*)d_in[0];
    const long long* idx = (const long long*)d_in[1];
    float*           out = (float*)d_out;
    float*           pos = (float*)d_ws;   // B_*L_ floats = 128 KiB scratch

    pos_kernel<<<B_, 256, 0, stream>>>(idx, pos);

    // B*L*16 threads: 8 quads x 2 head-halves per (b,l)
    const size_t total_threads = (size_t)B_ * L_ * 16;      // 524288
    const int    blocks        = (int)(total_threads / 256); // 2048
    rope_kernel<<<blocks, 256, 0, stream>>>(x, pos, out);
}

// Round 3
// 55.542 us; speedup vs baseline: 1.5086x; 1.5086x over previous
//
#include <hip/hip_runtime.h>
#include <cmath>

#define B_ 4
#define L_ 8192
#define N_ 16
#define H_ 64

typedef float f32x4 __attribute__((ext_vector_type(4)));

// ---------------------------------------------------------------------------
// Kernel A: per-row segment-reset positions. 1024 threads/block, one block
// per batch row.
//  1. per-thread scan of 8 lengths; wave shfl-scan; tiny cross-wave scan
//  2. inclusive csum (int) in LDS
//  3. branchless searchsorted-right: 13 fixed steps, 8 independent queries
//     per thread (ILP hides LDS latency)
// ---------------------------------------------------------------------------
__global__ __launch_bounds__(1024)
void pos_kernel(const long long* __restrict__ idx, float* __restrict__ pos) {
    __shared__ int csum[L_];
    __shared__ int wp[17];
    const int b   = blockIdx.x;
    const int tid = threadIdx.x;            // 1024 threads
    constexpr int CHUNK = L_ / 1024;        // 8

    const long long* row = idx + (size_t)b * L_;

    // local inclusive scan of this thread's 8 lengths
    int local[CHUNK];
    int s = 0;
#pragma unroll
    for (int i = 0; i < CHUNK; ++i) {
        s += (int)row[tid * CHUNK + i];
        local[i] = s;
    }

    // inclusive wave scan of per-thread totals
    const int lane = tid & 63, wv = tid >> 6;   // 16 waves
    int scan = s;
#pragma unroll
    for (int off = 1; off < 64; off <<= 1) {
        int n = __shfl_up(scan, off);
        if (lane >= off) scan += n;
    }
    if (lane == 63) wp[wv + 1] = scan;
    if (tid == 0)   wp[0] = 0;
    __syncthreads();
    if (tid == 0) {                             // 16 partials: trivial
        int a = 0;
        for (int i = 1; i <= 16; ++i) { a += wp[i]; wp[i] = a; }
    }
    __syncthreads();

    const int off0 = wp[wv] + (scan - s);       // exclusive prefix for thread
#pragma unroll
    for (int i = 0; i < CHUNK; ++i) csum[tid * CHUNK + i] = off0 + local[i];
    __syncthreads();

    const int total = csum[L_ - 1];

    // branchless searchsorted(csum, j, side='right') = count of entries <= j
    int p[CHUNK];
#pragma unroll
    for (int u = 0; u < CHUNK; ++u) p[u] = 0;
#pragma unroll
    for (int k = L_ / 2; k > 0; k >>= 1) {
#pragma unroll
        for (int u = 0; u < CHUNK; ++u) {
            const int j = tid + u * 1024;
            p[u] += (csum[p[u] + k - 1] <= j) ? k : 0;
        }
    }
#pragma unroll
    for (int u = 0; u < CHUNK; ++u) {
        const int j    = tid + u * 1024;
        const int excl = p[u] ? csum[p[u] - 1] : 0;   // segment start offset
        pos[(size_t)b * L_ + j] = (j < total) ? (float)(j - excl) : 0.f;
    }
}

// ---------------------------------------------------------------------------
// Kernel B: streaming RoPE, trig amortized over 8 heads per thread,
// NONTEMPORAL loads/stores (no reuse in either 128 MB stream; avoid L2/L3
// allocation churn between the read and write streams).
//   out[h]    = x[h]*cos - x[h+32]*sin
//   out[h+32] = x[h+32]*cos + x[h]*sin
// ---------------------------------------------------------------------------
__global__ void rope_kernel(const float* __restrict__ x,
                            const float* __restrict__ pos,
                            float* __restrict__ out) {
    const size_t t  = (size_t)blockIdx.x * blockDim.x + threadIdx.x;
    const int    q  = (int)(t & 7);        // which quad of the 32 pairs
    const int    hh = (int)((t >> 3) & 1); // head half (0: n=0..7, 1: n=8..15)
    const size_t bl = t >> 4;              // b*L + l

    const float p = pos[bl];

    // inv_freq[k] = 10000^(-k/32); phase in revolutions = p*inv_freq/(2*pi)
    constexpr float NEG_LN_BASE_OVER_32 = -0.28782313662425f; // -ln(10000)/32
    constexpr float INV_2PI             = 0.15915493667126f;  // 1/(2*pi)

    float sv[4], cv[4];
#pragma unroll
    for (int j = 0; j < 4; ++j) {
        const float f  = __expf((float)(q * 4 + j) * NEG_LN_BASE_OVER_32);
        float ph = p * f * INV_2PI;
        ph -= floorf(ph);                  // v_fract-style reduction
        sv[j] = __builtin_amdgcn_sinf(ph); // v_sin_f32: sin(2*pi*ph)
        cv[j] = __builtin_amdgcn_cosf(ph); // v_cos_f32
    }

    const size_t base0 = (bl * N_ + (size_t)(hh * 8)) * H_ + (size_t)(q * 4);
#pragma unroll
    for (int n = 0; n < 8; ++n) {
        const size_t base = base0 + (size_t)n * H_;
        const f32x4 a = __builtin_nontemporal_load((const f32x4*)(x + base));
        const f32x4 b = __builtin_nontemporal_load((const f32x4*)(x + base + 32));
        f32x4 o1, o2;
#pragma unroll
        for (int j = 0; j < 4; ++j) {
            const float xa = a[j];
            const float xb = b[j];
            o1[j] = xa * cv[j] - xb * sv[j];
            o2[j] = xb * cv[j] + xa * sv[j];
        }
        __builtin_nontemporal_store(o1, (f32x4*)(out + base));
        __builtin_nontemporal_store(o2, (f32x4*)(out + base + 32));
    }
}

extern "C" void kernel_launch(void* const* d_in, const int* in_sizes, int n_in,
                              void* d_out, int out_size, void* d_ws, size_t ws_size,
                              hipStream_t stream) {
    const float*     x   = (const float*)d_in[0];
    const long long* idx = (const long long*)d_in[1];
    float*           out = (float*)d_out;
    float*           pos = (float*)d_ws;   // B_*L_ floats = 128 KiB scratch

    pos_kernel<<<B_, 1024, 0, stream>>>(idx, pos);

    // B*L*16 threads: 8 quads x 2 head-halves per (b,l)
    const size_t total_threads = (size_t)B_ * L_ * 16;      // 524288
    const int    blocks        = (int)(total_threads / 256); // 2048
    rope_kernel<<<blocks, 256, 0, stream>>>(x, pos, out);
}